// Round 2
// baseline (7361.719 us; speedup 1.0000x reference)
//
#include <hip/hip_runtime.h>
#include <stdint.h>

typedef unsigned short u16;
typedef unsigned int u32;
typedef __attribute__((ext_vector_type(8))) short short8;   // 8 x bf16
typedef __attribute__((ext_vector_type(4))) float f32x4;
typedef __attribute__((ext_vector_type(4))) int int4v;

#define SEQ 256
#define NWG 73          // 64 gate + 8 d + 1 y
#define GATE_WGS 64
#define D_WGS 8

__device__ __forceinline__ u16 f2bf(float f) {
  u32 u = __float_as_uint(f);
  u += 0x7FFFu + ((u >> 16) & 1u);
  return (u16)(u >> 16);
}
__device__ __forceinline__ short8 cvt8(const float* __restrict__ p) {
  short8 r;
#pragma unroll
  for (int j = 0; j < 8; ++j) r[j] = (short)f2bf(p[j]);
  return r;
}
__device__ __forceinline__ float fast_tanh(float x) {
  return 1.0f - 2.0f / (1.0f + __expf(2.0f * x));
}
__device__ __forceinline__ float fast_sig(float x) {
  return 1.0f / (1.0f + __expf(-x));
}

__device__ __forceinline__ void grid_barrier(u32* cnt, u32* flg, int t) {
  __syncthreads();
  if (threadIdx.x == 0) {
    __threadfence();  // release (agent scope; wbL2 so cross-XCD readers see our stores)
    u32 target = (u32)(t + 1) * NWG;
    u32 prev = __hip_atomic_fetch_add(cnt, 1u, __ATOMIC_ACQ_REL, __HIP_MEMORY_SCOPE_AGENT);
    if (prev == target - 1u) {
      __hip_atomic_store(flg, (u32)(t + 1), __ATOMIC_RELEASE, __HIP_MEMORY_SCOPE_AGENT);
    } else {
      while (__hip_atomic_load(flg, __ATOMIC_RELAXED, __HIP_MEMORY_SCOPE_AGENT) < (u32)(t + 1))
        __builtin_amdgcn_s_sleep(2);
    }
    __threadfence();  // acquire (invalidate L1 + stale L2 lines)
  }
  __syncthreads();
}

// ---------------------------------------------------------------------------
// Prep: feat_0 = tanh(x[0]@Wfx^T + b_fx) -> Abuf0 (bf16 A-fragment layout),
// zero h-section of Abuf0, zero dflags + barrier state.
// A-frag chunk layout: chunk = (kb*4 + mt)*64 + lane; lane holds
// A[m = mt*16 + (lane&15)][k = kb*32 + (lane>>4)*8 + j], j=0..7.
// ---------------------------------------------------------------------------
__global__ void prep_kernel(const float* __restrict__ x, const float* __restrict__ W_fx,
                            const float* __restrict__ b_fx,
                            u16* __restrict__ Abuf0, int* __restrict__ dflag,
                            u32* __restrict__ bar) {
  int b = blockIdx.x, tid = threadIdx.x;
  if (b < 64) {
    int gidx = b * 256 + tid;          // 16384 elements of feat_0 [64][256]
    int chunk = gidx >> 3, j = gidx & 7;
    int kb = chunk >> 8, mt = (chunk >> 6) & 3, l = chunk & 63;
    int m = mt * 16 + (l & 15);
    int c = kb * 32 + (l >> 4) * 8 + j;
    float s = b_fx[c];
    const float* xr = x + m * 64;      // t = 0
    const float* wr = W_fx + c * 64;
    for (int k = 0; k < 64; ++k) s += xr[k] * wr[k];
    Abuf0[chunk * 8 + j] = f2bf(fast_tanh(s));
  } else {
    for (int it = 0; it < 16; ++it) {  // zero h-section: chunks 2048..6143
      int chunk = it * 256 + tid;
      *(int4v*)(Abuf0 + (2048 + chunk) * 8) = (int4v){0, 0, 0, 0};
    }
    dflag[tid] = 0;
    if (tid == 0) { bar[0] = 0u; bar[1] = 0u; }
  }
}

// ---------------------------------------------------------------------------
// Persistent recurrent kernel. 73 WGs x 256 threads (co-resident on 256 CUs).
// ---------------------------------------------------------------------------
__global__ void __launch_bounds__(256, 1)
rnn_kernel(const float* __restrict__ x, const float* __restrict__ msel,
           const float* __restrict__ W_fx, const float* __restrict__ b_fx,
           const float* __restrict__ W_ih, const float* __restrict__ W_hh,
           const float* __restrict__ b_ih, const float* __restrict__ b_hh,
           const float* __restrict__ W_hx, const float* __restrict__ b_hx,
           const float* __restrict__ W_out, const float* __restrict__ b_out,
           float* __restrict__ out,
           u16* __restrict__ Abuf0, u16* __restrict__ Abuf1,
           u16* __restrict__ dbuf, int* __restrict__ dflag, u32* __restrict__ bar) {
  __shared__ __attribute__((aligned(16))) char smem[60672];
  const int wgid = blockIdx.x;
  const int tid = threadIdx.x;
  const int wv = tid >> 6, ln = tid & 63;
  u32* barcnt = bar;
  u32* barflg = bar + 1;

  if (wgid < GATE_WGS) {
    // ===== gate WG: 8 hidden units -> 32 gate columns (i,f,g,o x 8) =====
    const int wg = wgid;
    u16* Bf = (u16*)smem;                      // [24 kb][2 nt][64][8] bf16 = 48KB
    float* red = (float*)(smem + 49152);       // [8 tile][64][4] f32 = 8KB
    float* bsum = (float*)(smem + 57344);      // [32]
    for (int it = 0; it < 12; ++it) {          // f32 weights -> bf16 frags in LDS
      int chunk = it * 256 + tid;              // [kb(24)][nt(2)][lane(64)]
      int kb = chunk >> 7, nt = (chunk >> 6) & 1, l = chunk & 63;
      int n = l & 15, q = l >> 4;
      int gate = nt * 2 + (n >> 3);
      int unit = n & 7;
      int row = gate * 512 + wg * 8 + unit;
      int k = kb * 32 + q * 8;
      const float* src = (k < 256) ? (W_ih + row * 256 + k) : (W_hh + row * 512 + (k - 256));
      *(short8*)(Bf + chunk * 8) = cvt8(src);
    }
    if (tid < 32) {
      int gate = tid >> 3, unit = tid & 7;
      int row = gate * 512 + wg * 8 + unit;
      bsum[tid] = b_ih[row] + b_hh[row];
    }
    float creg[2] = {0.f, 0.f};                // c-state in registers
    __syncthreads();

    for (int t = 0; t < SEQ; ++t) {
      const u16* A = (t & 1) ? Abuf1 : Abuf0;
      u16* An = (t & 1) ? Abuf0 : Abuf1;
      f32x4 acc[2][4];
#pragma unroll
      for (int nt = 0; nt < 2; nt++)
#pragma unroll
        for (int mt = 0; mt < 4; mt++) acc[nt][mt] = (f32x4){0.f, 0.f, 0.f, 0.f};
#pragma unroll
      for (int kk = 0; kk < 6; ++kk) {         // wave K-split: kb in [6wv, 6wv+6)
        int kb = wv * 6 + kk;
        short8 a[4], bfr[2];
#pragma unroll
        for (int mt = 0; mt < 4; mt++)
          a[mt] = *(const short8*)(A + ((kb * 4 + mt) * 64 + ln) * 8);
#pragma unroll
        for (int nt = 0; nt < 2; nt++)
          bfr[nt] = *(const short8*)(Bf + ((kb * 2 + nt) * 64 + ln) * 8);
#pragma unroll
        for (int nt = 0; nt < 2; nt++)
#pragma unroll
          for (int mt = 0; mt < 4; mt++)
            acc[nt][mt] = __builtin_amdgcn_mfma_f32_16x16x32_bf16(a[mt], bfr[nt], acc[nt][mt], 0, 0, 0);
      }
      // cross-wave K reduction into wave 0
#pragma unroll
      for (int r = 1; r < 4; ++r) {
        if (wv == r)
          for (int nt = 0; nt < 2; nt++)
            for (int mt = 0; mt < 4; mt++)
              *(f32x4*)(red + ((nt * 4 + mt) * 64 + ln) * 4) = acc[nt][mt];
        __syncthreads();
        if (wv == 0)
          for (int nt = 0; nt < 2; nt++)
            for (int mt = 0; mt < 4; mt++)
              acc[nt][mt] += *(const f32x4*)(red + ((nt * 4 + mt) * 64 + ln) * 4);
        __syncthreads();
      }
      if (wv == 0)
        for (int nt = 0; nt < 2; nt++)
          for (int mt = 0; mt < 4; mt++)
            *(f32x4*)(red + ((nt * 4 + mt) * 64 + ln) * 4) = acc[nt][mt];
      __syncthreads();
      // LSTM cell: 512 (m,u) items, 2 per thread
#pragma unroll
      for (int it = 0; it < 2; ++it) {
        int item = it * 256 + tid;
        int m = item >> 3, u = item & 7;
        int mt = m >> 4, lq = ((m & 15) >> 2) * 16, reg = m & 3;
        float g4[4];
#pragma unroll
        for (int g = 0; g < 4; ++g) {
          int nt = g >> 1, c = (g & 1) * 8 + u;
          g4[g] = red[(((nt * 4 + mt) * 64) + lq + c) * 4 + reg] + bsum[g * 8 + u];
        }
        float ii = fast_sig(g4[0]), ff = fast_sig(g4[1]);
        float gg = fast_tanh(g4[2]), oo = fast_sig(g4[3]);
        float cn = ff * creg[it] + ii * gg;
        creg[it] = cn;
        float h = oo * fast_tanh(cn);
        int U = wg * 8 + u;
        int kb = 8 + (U >> 5), q = (U & 31) >> 3, j = U & 7;
        An[((kb * 4 + mt) * 64 + q * 16 + (m & 15)) * 8 + j] = f2bf(h);
      }
      grid_barrier(barcnt, barflg, t);
    }
  } else if (wgid < GATE_WGS + D_WGS) {
    // ===== d WG: d = tanh(h @ Whx^T + b_hx), 32 DEC columns =====
    const int dw = wgid - GATE_WGS;
    u16* Bf = (u16*)smem;                      // [16 kb][2 nt][64][8] = 32KB
    float* red = (float*)(smem + 32768);       // 8KB
    float* bias = (float*)(smem + 40960);      // [32]
    for (int it = 0; it < 8; ++it) {
      int chunk = it * 256 + tid;
      int kb = chunk >> 7, nt = (chunk >> 6) & 1, l = chunk & 63;
      int n = l & 15, q = l >> 4;
      int row = dw * 32 + nt * 16 + n;
      int k = kb * 32 + q * 8;
      *(short8*)(Bf + chunk * 8) = cvt8(W_hx + row * 512 + k);
    }
    if (tid < 32) bias[tid] = b_hx[dw * 32 + tid];
    __syncthreads();

    for (int t = 0; t < SEQ; ++t) {
      const u16* A = (t & 1) ? Abuf1 : Abuf0;
      f32x4 acc[2][4];
#pragma unroll
      for (int nt = 0; nt < 2; nt++)
#pragma unroll
        for (int mt = 0; mt < 4; mt++) acc[nt][mt] = (f32x4){0.f, 0.f, 0.f, 0.f};
#pragma unroll
      for (int kk = 0; kk < 4; ++kk) {         // K=512 (h section), kb' in [4wv,4wv+4)
        int kbh = wv * 4 + kk;
        short8 a[4], bfr[2];
#pragma unroll
        for (int mt = 0; mt < 4; mt++)
          a[mt] = *(const short8*)(A + (((8 + kbh) * 4 + mt) * 64 + ln) * 8);
#pragma unroll
        for (int nt = 0; nt < 2; nt++)
          bfr[nt] = *(const short8*)(Bf + ((kbh * 2 + nt) * 64 + ln) * 8);
#pragma unroll
        for (int nt = 0; nt < 2; nt++)
#pragma unroll
          for (int mt = 0; mt < 4; mt++)
            acc[nt][mt] = __builtin_amdgcn_mfma_f32_16x16x32_bf16(a[mt], bfr[nt], acc[nt][mt], 0, 0, 0);
      }
#pragma unroll
      for (int r = 1; r < 4; ++r) {
        if (wv == r)
          for (int nt = 0; nt < 2; nt++)
            for (int mt = 0; mt < 4; mt++)
              *(f32x4*)(red + ((nt * 4 + mt) * 64 + ln) * 4) = acc[nt][mt];
        __syncthreads();
        if (wv == 0)
          for (int nt = 0; nt < 2; nt++)
            for (int mt = 0; mt < 4; mt++)
              acc[nt][mt] += *(const f32x4*)(red + ((nt * 4 + mt) * 64 + ln) * 4);
        __syncthreads();
      }
      if (wv == 0)
        for (int nt = 0; nt < 2; nt++)
          for (int mt = 0; mt < 4; mt++)
            *(f32x4*)(red + ((nt * 4 + mt) * 64 + ln) * 4) = acc[nt][mt];
      __syncthreads();
#pragma unroll
      for (int it = 0; it < 8; ++it) {         // tanh + write d (A-frag layout, kb == dw)
        int item = it * 256 + tid;
        int m = item >> 5, c = item & 31;
        int mt = m >> 4, nt = c >> 4;
        int lq = ((m & 15) >> 2) * 16, reg = m & 3;
        float v = fast_tanh(red[(((nt * 4 + mt) * 64) + lq + (c & 15)) * 4 + reg] + bias[c]);
        int q = c >> 3, j = c & 7;
        dbuf[((dw * 4 + mt) * 64 + q * 16 + (m & 15)) * 8 + j] = f2bf(v);
      }
      __syncthreads();
      if (tid == 0)
        __hip_atomic_fetch_add(&dflag[t], 1, __ATOMIC_RELEASE, __HIP_MEMORY_SCOPE_AGENT);
      grid_barrier(barcnt, barflg, t);
    }
  } else {
    // ===== y WG: y = d@Wout^T + b_out; feat_{t+1} = mix*fe(y) + (1-mix)*fe(x[t+1])
    float* red = (float*)smem;                 // [16][64][4] = 16KB
    u16* ystage = (u16*)(smem + 16384);        // [64][80] bf16
    u16* fstage = (u16*)(smem + 26624);        // [64][264] bf16

    for (int t = 0; t < SEQ; ++t) {
      u16* An = (t & 1) ? Abuf0 : Abuf1;
      if (tid == 0) {
        while (__hip_atomic_load(&dflag[t], __ATOMIC_RELAXED, __HIP_MEMORY_SCOPE_AGENT) < D_WGS)
          __builtin_amdgcn_s_sleep(2);
        __threadfence();
      }
      __syncthreads();
      // y GEMM: M=64 N=64 K=256
      f32x4 acc[4][4];
#pragma unroll
      for (int nt = 0; nt < 4; nt++)
#pragma unroll
        for (int mt = 0; mt < 4; mt++) acc[nt][mt] = (f32x4){0.f, 0.f, 0.f, 0.f};
#pragma unroll
      for (int kk = 0; kk < 2; ++kk) {
        int kb = wv * 2 + kk;
        int koff = kb * 32 + (ln >> 4) * 8;
        short8 a[4], bfr[4];
#pragma unroll
        for (int mt = 0; mt < 4; mt++)
          a[mt] = *(const short8*)(dbuf + ((kb * 4 + mt) * 64 + ln) * 8);
#pragma unroll
        for (int nt = 0; nt < 4; nt++)
          bfr[nt] = cvt8(W_out + (nt * 16 + (ln & 15)) * 256 + koff);
#pragma unroll
        for (int nt = 0; nt < 4; nt++)
#pragma unroll
          for (int mt = 0; mt < 4; mt++)
            acc[nt][mt] = __builtin_amdgcn_mfma_f32_16x16x32_bf16(a[mt], bfr[nt], acc[nt][mt], 0, 0, 0);
      }
#pragma unroll
      for (int r = 1; r < 4; ++r) {
        if (wv == r)
          for (int nt = 0; nt < 4; nt++)
            for (int mt = 0; mt < 4; mt++)
              *(f32x4*)(red + ((nt * 4 + mt) * 64 + ln) * 4) = acc[nt][mt];
        __syncthreads();
        if (wv == 0)
          for (int nt = 0; nt < 4; nt++)
            for (int mt = 0; mt < 4; mt++)
              acc[nt][mt] += *(const f32x4*)(red + ((nt * 4 + mt) * 64 + ln) * 4);
        __syncthreads();
      }
      if (wv == 0) {
        int q = ln >> 4, c15 = ln & 15;
        for (int nt = 0; nt < 4; nt++)
          for (int mt = 0; mt < 4; mt++) {
            float bo = b_out[nt * 16 + c15];
#pragma unroll
            for (int r2 = 0; r2 < 4; r2++) {
              float yv = acc[nt][mt][r2] + bo;
              int row = mt * 16 + q * 4 + r2;
              out[t * 4096 + row * 64 + nt * 16 + c15] = yv;      // f32 output
              ystage[row * 80 + nt * 16 + c15] = f2bf(yv);
            }
          }
      }
      __syncthreads();
      if (t < SEQ - 1) {
        // fused fe(y_t) and fe(x[t+1]); wave wv handles feat cols [64wv, 64wv+64)
        f32x4 au[4][4], tf[4][4];
#pragma unroll
        for (int ntl = 0; ntl < 4; ntl++)
#pragma unroll
          for (int mt = 0; mt < 4; mt++) {
            au[ntl][mt] = (f32x4){0.f, 0.f, 0.f, 0.f};
            tf[ntl][mt] = (f32x4){0.f, 0.f, 0.f, 0.f};
          }
#pragma unroll
        for (int kb = 0; kb < 2; ++kb) {
          int koff = kb * 32 + (ln >> 4) * 8;
          short8 ya[4], xa[4], wb[4];
#pragma unroll
          for (int mt = 0; mt < 4; mt++) {
            int m = mt * 16 + (ln & 15);
            ya[mt] = *(const short8*)(ystage + m * 80 + koff);
            xa[mt] = cvt8(x + ((t + 1) * 64 + m) * 64 + koff);
          }
#pragma unroll
          for (int ntl = 0; ntl < 4; ntl++)
            wb[ntl] = cvt8(W_fx + ((wv * 4 + ntl) * 16 + (ln & 15)) * 64 + koff);
#pragma unroll
          for (int ntl = 0; ntl < 4; ntl++)
#pragma unroll
            for (int mt = 0; mt < 4; mt++) {
              au[ntl][mt] = __builtin_amdgcn_mfma_f32_16x16x32_bf16(ya[mt], wb[ntl], au[ntl][mt], 0, 0, 0);
              tf[ntl][mt] = __builtin_amdgcn_mfma_f32_16x16x32_bf16(xa[mt], wb[ntl], tf[ntl][mt], 0, 0, 0);
            }
        }
        float mix = msel[t + 1];
        int q = ln >> 4, c15 = ln & 15;
        for (int ntl = 0; ntl < 4; ntl++)
          for (int mt = 0; mt < 4; mt++) {
            float bfx0 = b_fx[(wv * 4 + ntl) * 16 + c15];
#pragma unroll
            for (int r2 = 0; r2 < 4; r2++) {
              float f = mix * fast_tanh(au[ntl][mt][r2] + bfx0) +
                        (1.f - mix) * fast_tanh(tf[ntl][mt][r2] + bfx0);
              int row = mt * 16 + q * 4 + r2;
              fstage[row * 264 + (wv * 4 + ntl) * 16 + c15] = f2bf(f);
            }
          }
        __syncthreads();
#pragma unroll
        for (int it = 0; it < 8; ++it) {       // fstage -> An feat section (A-frag)
          int chunk = it * 256 + tid;
          int kb = chunk >> 8, l = chunk & 63;
          int m = ((chunk >> 6) & 3) * 16 + (l & 15);
          int k = kb * 32 + (l >> 4) * 8;
          *(short8*)(An + chunk * 8) = *(const short8*)(fstage + m * 264 + k);
        }
      }
      grid_barrier(barcnt, barflg, t);
    }
  }
}

extern "C" void kernel_launch(void* const* d_in, const int* in_sizes, int n_in,
                              void* d_out, int out_size, void* d_ws, size_t ws_size,
                              hipStream_t stream) {
  const float* x     = (const float*)d_in[0];
  const float* msel  = (const float*)d_in[1];
  const float* W_fx  = (const float*)d_in[2];
  const float* b_fx  = (const float*)d_in[3];
  const float* W_ih  = (const float*)d_in[4];
  const float* W_hh  = (const float*)d_in[5];
  const float* b_ih  = (const float*)d_in[6];
  const float* b_hh  = (const float*)d_in[7];
  const float* W_hx  = (const float*)d_in[8];
  const float* b_hx  = (const float*)d_in[9];
  const float* W_out = (const float*)d_in[10];
  const float* b_out = (const float*)d_in[11];

  uint8_t* ws = (uint8_t*)d_ws;
  u16* Abuf0 = (u16*)ws;                    // 98304 B  bf16 A-frag [24][4][64][8]
  u16* Abuf1 = (u16*)(ws + 98304);          // 98304 B
  u16* dbuf  = (u16*)(ws + 196608);         // 32768 B  bf16 d-frag [8][4][64][8]
  int* dflag = (int*)(ws + 229376);         // 1024 B
  u32* bar   = (u32*)(ws + 230400);         // 8 B

  prep_kernel<<<65, 256, 0, stream>>>(x, W_fx, b_fx, Abuf0, dflag, bar);
  rnn_kernel<<<NWG, 256, 0, stream>>>(x, msel, W_fx, b_fx, W_ih, W_hh, b_ih, b_hh,
                                      W_hx, b_hx, W_out, b_out,
                                      (float*)d_out, Abuf0, Abuf1, dbuf, dflag, bar);
}

// Round 3
// 6063.423 us; speedup vs baseline: 1.2141x; 1.2141x over previous
//
#include <hip/hip_runtime.h>
#include <stdint.h>

typedef unsigned short u16;
typedef unsigned int u32;
typedef __attribute__((ext_vector_type(8))) short short8;   // 8 x bf16
typedef __attribute__((ext_vector_type(4))) float f32x4;
typedef __attribute__((ext_vector_type(4))) int int4v;

#define SEQ 256
#define GATE_WGS 64
#define D_WGS 8
#define NWG 73          // 64 gate + 8 d + 1 y

// ws layout (bytes):
//   Abuf ring[3] : 3 * 98304           @ 0        (bf16 A-frag [24kb][4mt][64][8])
//   dbuf ring[2] : 2 * 32768           @ 294912   (bf16 d-frag [8kb][4mt][64][8])
//   WoutB bf16   : 32768               @ 360448   ([64][256] row-major)
//   WfxB  bf16   : 32768               @ 393216   ([256][64] row-major)
//   flags u32    : 4672                @ 425984   (hflag[64]x16stride, dflag[8]x16, fc)
#define A_ELE 49152
#define D_ELE 16384

__device__ __forceinline__ u16 f2bf(float f) {
  u32 u = __float_as_uint(f);
  u += 0x7FFFu + ((u >> 16) & 1u);
  return (u16)(u >> 16);
}
__device__ __forceinline__ short8 cvt8(const float* __restrict__ p) {
  short8 r;
#pragma unroll
  for (int j = 0; j < 8; ++j) r[j] = (short)f2bf(p[j]);
  return r;
}
__device__ __forceinline__ float fast_tanh(float x) {
  return 1.0f - 2.0f / (1.0f + __expf(2.0f * x));
}
__device__ __forceinline__ float fast_sig(float x) {
  return 1.0f / (1.0f + __expf(-x));
}
// monotonic flag helpers: no RMW, distinct cachelines, release/acquire via threadfence
__device__ __forceinline__ void pollge(u32* p, u32 v) {
  while (__hip_atomic_load(p, __ATOMIC_RELAXED, __HIP_MEMORY_SCOPE_AGENT) < v)
    __builtin_amdgcn_s_sleep(1);
}
__device__ __forceinline__ void setflag(u32* p, u32 v) {
  __threadfence();   // release: drain stores + wbL2 so remote XCDs see our data
  __hip_atomic_store(p, v, __ATOMIC_RELAXED, __HIP_MEMORY_SCOPE_AGENT);
}

// ---------------------------------------------------------------------------
// Prep: feat_0 -> Abuf[0] feat section; zero Abuf[0] h section; zero flags;
// convert W_out / W_fx f32 -> bf16 staging in ws.
// A-frag chunk layout: chunk = (kb*4 + mt)*64 + lane; lane holds
// A[m = mt*16 + (lane&15)][k = kb*32 + (lane>>4)*8 + j], j=0..7.
// ---------------------------------------------------------------------------
__global__ void prep_kernel(const float* __restrict__ x, const float* __restrict__ W_fx,
                            const float* __restrict__ b_fx,
                            const float* __restrict__ W_out,
                            u16* __restrict__ Abuf0, u16* __restrict__ WoutB,
                            u16* __restrict__ WfxB, u32* __restrict__ flags) {
  int b = blockIdx.x, tid = threadIdx.x;
  if (b < 64) {
    int gidx = b * 256 + tid;          // 16384 elements of feat_0 [64][256]
    int chunk = gidx >> 3, j = gidx & 7;
    int kb = chunk >> 8, mt = (chunk >> 6) & 3, l = chunk & 63;
    int m = mt * 16 + (l & 15);
    int c = kb * 32 + (l >> 4) * 8 + j;
    float s = b_fx[c];
    const float* xr = x + m * 64;      // t = 0
    const float* wr = W_fx + c * 64;
    for (int k = 0; k < 64; ++k) s += xr[k] * wr[k];
    Abuf0[chunk * 8 + j] = f2bf(fast_tanh(s));
  } else if (b == 64) {
    for (int it = 0; it < 16; ++it) {  // zero h-section of Abuf[0]: chunks 2048..6143
      int chunk = it * 256 + tid;
      *(int4v*)(Abuf0 + (2048 + chunk) * 8) = (int4v){0, 0, 0, 0};
    }
    for (int k = 0; k < 5; ++k) {      // zero 1168 flag words
      int i = k * 256 + tid;
      if (i < 1168) flags[i] = 0u;
    }
  } else if (b == 65) {
    for (int k = 0; k < 64; ++k) { int i = k * 256 + tid; WoutB[i] = f2bf(W_out[i]); }
  } else {
    for (int k = 0; k < 64; ++k) { int i = k * 256 + tid; WfxB[i] = f2bf(W_fx[i]); }
  }
}

// ---------------------------------------------------------------------------
// Persistent recurrent kernel. 73 WGs x 256 threads (co-resident on 256 CUs).
// Point-to-point flags, no grid barrier:
//   hflag[wg] = s+1  after gate wg wrote h_{s+1}   (consumers need >= t for h_t)
//   dflag[dw] = s+1  after d wg wrote d_s          (y needs >= t+1)
//   fc        = s+1  after y wrote feat_{s+1}      (gates need >= t for feat_t)
// ---------------------------------------------------------------------------
__global__ void __launch_bounds__(256, 1)
rnn_kernel(const float* __restrict__ x, const float* __restrict__ msel,
           const float* __restrict__ W_fx, const float* __restrict__ b_fx,
           const float* __restrict__ W_ih, const float* __restrict__ W_hh,
           const float* __restrict__ b_ih, const float* __restrict__ b_hh,
           const float* __restrict__ W_hx, const float* __restrict__ b_hx,
           const float* __restrict__ b_out,
           float* __restrict__ out,
           u16* __restrict__ Abase, u16* __restrict__ dbase,
           const u16* __restrict__ WoutB, const u16* __restrict__ WfxB,
           u32* __restrict__ flags) {
  __shared__ __attribute__((aligned(16))) char smem[60672];
  const int wgid = blockIdx.x;
  const int tid = threadIdx.x;
  const int wv = tid >> 6, ln = tid & 63;
  u32* hflag = flags;          // stride 16 u32 (64B cachelines)
  u32* dflag = flags + 1024;
  u32* fcv   = flags + 1152;

  if (wgid < GATE_WGS) {
    // ===== gate WG: 8 hidden units -> 32 gate columns (i,f,g,o x 8) =====
    const int wg = wgid;
    u16* Bf = (u16*)smem;                      // [24 kb][2 nt][64][8] bf16 = 48KB
    float* red = (float*)(smem + 49152);       // [8 tile][64][4] f32 = 8KB
    float* bsum = (float*)(smem + 57344);      // [32]
    for (int it = 0; it < 12; ++it) {          // f32 weights -> bf16 frags in LDS
      int chunk = it * 256 + tid;              // [kb(24)][nt(2)][lane(64)]
      int kb = chunk >> 7, nt = (chunk >> 6) & 1, l = chunk & 63;
      int n = l & 15, q = l >> 4;
      int gate = nt * 2 + (n >> 3);
      int unit = n & 7;
      int row = gate * 512 + wg * 8 + unit;
      int k = kb * 32 + q * 8;
      const float* src = (k < 256) ? (W_ih + row * 256 + k) : (W_hh + row * 512 + (k - 256));
      *(short8*)(Bf + chunk * 8) = cvt8(src);
    }
    if (tid < 32) {
      int gate = tid >> 3, unit = tid & 7;
      int row = gate * 512 + wg * 8 + unit;
      bsum[tid] = b_ih[row] + b_hh[row];
    }
    float creg[2] = {0.f, 0.f};                // c-state in registers
    __syncthreads();

    int r = 0, rn = 1;
    for (int t = 0; t < SEQ; ++t) {
      // wait: h_t from all gates, feat_t from y
      if (tid < 64) pollge(&hflag[tid * 16], (u32)t);
      else if (tid == 64) pollge(fcv, (u32)t);
      __syncthreads();
      __threadfence();  // acquire: invalidate stale cached A lines
      const u16* A = Abase + r * A_ELE;
      u16* An = Abase + rn * A_ELE;
      f32x4 acc[2][4];
#pragma unroll
      for (int nt = 0; nt < 2; nt++)
#pragma unroll
        for (int mt = 0; mt < 4; mt++) acc[nt][mt] = (f32x4){0.f, 0.f, 0.f, 0.f};
#pragma unroll
      for (int kk = 0; kk < 6; ++kk) {         // wave K-split: kb in [6wv, 6wv+6)
        int kb = wv * 6 + kk;
        short8 a[4], bfr[2];
#pragma unroll
        for (int mt = 0; mt < 4; mt++)
          a[mt] = *(const short8*)(A + ((kb * 4 + mt) * 64 + ln) * 8);
#pragma unroll
        for (int nt = 0; nt < 2; nt++)
          bfr[nt] = *(const short8*)(Bf + ((kb * 2 + nt) * 64 + ln) * 8);
#pragma unroll
        for (int nt = 0; nt < 2; nt++)
#pragma unroll
          for (int mt = 0; mt < 4; mt++)
            acc[nt][mt] = __builtin_amdgcn_mfma_f32_16x16x32_bf16(a[mt], bfr[nt], acc[nt][mt], 0, 0, 0);
      }
      // cross-wave K reduction into wave 0
#pragma unroll
      for (int rr = 1; rr < 4; ++rr) {
        if (wv == rr)
          for (int nt = 0; nt < 2; nt++)
            for (int mt = 0; mt < 4; mt++)
              *(f32x4*)(red + ((nt * 4 + mt) * 64 + ln) * 4) = acc[nt][mt];
        __syncthreads();
        if (wv == 0)
          for (int nt = 0; nt < 2; nt++)
            for (int mt = 0; mt < 4; mt++)
              acc[nt][mt] += *(const f32x4*)(red + ((nt * 4 + mt) * 64 + ln) * 4);
        __syncthreads();
      }
      if (wv == 0)
        for (int nt = 0; nt < 2; nt++)
          for (int mt = 0; mt < 4; mt++)
            *(f32x4*)(red + ((nt * 4 + mt) * 64 + ln) * 4) = acc[nt][mt];
      __syncthreads();
      // LSTM cell: 512 (m,u) items, 2 per thread
#pragma unroll
      for (int it = 0; it < 2; ++it) {
        int item = it * 256 + tid;
        int m = item >> 3, u = item & 7;
        int mt = m >> 4, lq = ((m & 15) >> 2) * 16, reg = m & 3;
        float g4[4];
#pragma unroll
        for (int g = 0; g < 4; ++g) {
          int nt = g >> 1, c = (g & 1) * 8 + u;
          g4[g] = red[(((nt * 4 + mt) * 64) + lq + c) * 4 + reg] + bsum[g * 8 + u];
        }
        float ii = fast_sig(g4[0]), ff = fast_sig(g4[1]);
        float gg = fast_tanh(g4[2]), oo = fast_sig(g4[3]);
        float cn = ff * creg[it] + ii * gg;
        creg[it] = cn;
        float h = oo * fast_tanh(cn);
        int U = wg * 8 + u;
        int kb = 8 + (U >> 5), q = (U & 31) >> 3, j = U & 7;
        An[((kb * 4 + mt) * 64 + q * 16 + (m & 15)) * 8 + j] = f2bf(h);
      }
      __syncthreads();
      if (tid == 0) setflag(&hflag[wg * 16], (u32)(t + 1));
      r = rn; rn = (rn == 2) ? 0 : rn + 1;
    }
  } else if (wgid < GATE_WGS + D_WGS) {
    // ===== d WG: d = tanh(h @ Whx^T + b_hx), 32 DEC columns =====
    const int dw = wgid - GATE_WGS;
    u16* Bf = (u16*)smem;                      // [16 kb][2 nt][64][8] = 32KB
    float* red = (float*)(smem + 32768);       // 8KB
    float* bias = (float*)(smem + 40960);      // [32]
    for (int it = 0; it < 8; ++it) {
      int chunk = it * 256 + tid;
      int kb = chunk >> 7, nt = (chunk >> 6) & 1, l = chunk & 63;
      int n = l & 15, q = l >> 4;
      int row = dw * 32 + nt * 16 + n;
      int k = kb * 32 + q * 8;
      *(short8*)(Bf + chunk * 8) = cvt8(W_hx + row * 512 + k);
    }
    if (tid < 32) bias[tid] = b_hx[dw * 32 + tid];
    __syncthreads();

    int r = 0, rn = 1;
    for (int t = 0; t < SEQ; ++t) {
      if (tid < 64) pollge(&hflag[tid * 16], (u32)t);   // need h_t only
      __syncthreads();
      __threadfence();
      const u16* A = Abase + r * A_ELE;
      u16* dbufR = dbase + (t & 1) * D_ELE;
      f32x4 acc[2][4];
#pragma unroll
      for (int nt = 0; nt < 2; nt++)
#pragma unroll
        for (int mt = 0; mt < 4; mt++) acc[nt][mt] = (f32x4){0.f, 0.f, 0.f, 0.f};
#pragma unroll
      for (int kk = 0; kk < 4; ++kk) {         // K=512 (h section), kb' in [4wv,4wv+4)
        int kbh = wv * 4 + kk;
        short8 a[4], bfr[2];
#pragma unroll
        for (int mt = 0; mt < 4; mt++)
          a[mt] = *(const short8*)(A + (((8 + kbh) * 4 + mt) * 64 + ln) * 8);
#pragma unroll
        for (int nt = 0; nt < 2; nt++)
          bfr[nt] = *(const short8*)(Bf + ((kbh * 2 + nt) * 64 + ln) * 8);
#pragma unroll
        for (int nt = 0; nt < 2; nt++)
#pragma unroll
          for (int mt = 0; mt < 4; mt++)
            acc[nt][mt] = __builtin_amdgcn_mfma_f32_16x16x32_bf16(a[mt], bfr[nt], acc[nt][mt], 0, 0, 0);
      }
#pragma unroll
      for (int rr = 1; rr < 4; ++rr) {
        if (wv == rr)
          for (int nt = 0; nt < 2; nt++)
            for (int mt = 0; mt < 4; mt++)
              *(f32x4*)(red + ((nt * 4 + mt) * 64 + ln) * 4) = acc[nt][mt];
        __syncthreads();
        if (wv == 0)
          for (int nt = 0; nt < 2; nt++)
            for (int mt = 0; mt < 4; mt++)
              acc[nt][mt] += *(const f32x4*)(red + ((nt * 4 + mt) * 64 + ln) * 4);
        __syncthreads();
      }
      if (wv == 0)
        for (int nt = 0; nt < 2; nt++)
          for (int mt = 0; mt < 4; mt++)
            *(f32x4*)(red + ((nt * 4 + mt) * 64 + ln) * 4) = acc[nt][mt];
      __syncthreads();
#pragma unroll
      for (int it = 0; it < 8; ++it) {         // tanh + write d (A-frag layout, kb == dw)
        int item = it * 256 + tid;
        int m = item >> 5, c = item & 31;
        int mt = m >> 4, nt = c >> 4;
        int lq = ((m & 15) >> 2) * 16, reg = m & 3;
        float v = fast_tanh(red[(((nt * 4 + mt) * 64) + lq + (c & 15)) * 4 + reg] + bias[c]);
        int q = c >> 3, j = c & 7;
        dbufR[((dw * 4 + mt) * 64 + q * 16 + (m & 15)) * 8 + j] = f2bf(v);
      }
      __syncthreads();
      if (tid == 0) setflag(&dflag[dw * 16], (u32)(t + 1));
      r = rn; rn = (rn == 2) ? 0 : rn + 1;
    }
  } else {
    // ===== y WG: y = d@Wout^T + b_out; feat_{t+1} = mix*fe(y) + (1-mix)*fe(x[t+1])
    float* red = (float*)smem;                 // [16][64][4] = 16KB
    u16* ystage = (u16*)(smem + 16384);        // [64][80] bf16
    u16* fstage = (u16*)(smem + 26624);        // [64][264] bf16

    int rn = 1;
    for (int t = 0; t < SEQ; ++t) {
      if (tid < 8) pollge(&dflag[tid * 16], (u32)(t + 1));
      __syncthreads();
      __threadfence();
      const u16* dbufR = dbase + (t & 1) * D_ELE;
      u16* An = Abase + rn * A_ELE;
      // y GEMM: M=64 N=64 K=256
      f32x4 acc[4][4];
#pragma unroll
      for (int nt = 0; nt < 4; nt++)
#pragma unroll
        for (int mt = 0; mt < 4; mt++) acc[nt][mt] = (f32x4){0.f, 0.f, 0.f, 0.f};
#pragma unroll
      for (int kk = 0; kk < 2; ++kk) {
        int kb = wv * 2 + kk;
        int koff = kb * 32 + (ln >> 4) * 8;
        short8 a[4], bfr[4];
#pragma unroll
        for (int mt = 0; mt < 4; mt++)
          a[mt] = *(const short8*)(dbufR + ((kb * 4 + mt) * 64 + ln) * 8);
#pragma unroll
        for (int nt = 0; nt < 4; nt++)
          bfr[nt] = *(const short8*)(WoutB + (nt * 16 + (ln & 15)) * 256 + koff);
#pragma unroll
        for (int nt = 0; nt < 4; nt++)
#pragma unroll
          for (int mt = 0; mt < 4; mt++)
            acc[nt][mt] = __builtin_amdgcn_mfma_f32_16x16x32_bf16(a[mt], bfr[nt], acc[nt][mt], 0, 0, 0);
      }
#pragma unroll
      for (int rr = 1; rr < 4; ++rr) {
        if (wv == rr)
          for (int nt = 0; nt < 4; nt++)
            for (int mt = 0; mt < 4; mt++)
              *(f32x4*)(red + ((nt * 4 + mt) * 64 + ln) * 4) = acc[nt][mt];
        __syncthreads();
        if (wv == 0)
          for (int nt = 0; nt < 4; nt++)
            for (int mt = 0; mt < 4; mt++)
              acc[nt][mt] += *(const f32x4*)(red + ((nt * 4 + mt) * 64 + ln) * 4);
        __syncthreads();
      }
      if (wv == 0) {
        int q = ln >> 4, c15 = ln & 15;
        for (int nt = 0; nt < 4; nt++)
          for (int mt = 0; mt < 4; mt++) {
            float bo = b_out[nt * 16 + c15];
#pragma unroll
            for (int r2 = 0; r2 < 4; r2++) {
              float yv = acc[nt][mt][r2] + bo;
              int row = mt * 16 + q * 4 + r2;
              out[t * 4096 + row * 64 + nt * 16 + c15] = yv;      // f32 output
              ystage[row * 80 + nt * 16 + c15] = f2bf(yv);
            }
          }
      }
      __syncthreads();
      if (t < SEQ - 1) {
        // fused fe(y_t) and fe(x[t+1]); wave wv handles feat cols [64wv, 64wv+64)
        f32x4 au[4][4], tf[4][4];
#pragma unroll
        for (int ntl = 0; ntl < 4; ntl++)
#pragma unroll
          for (int mt = 0; mt < 4; mt++) {
            au[ntl][mt] = (f32x4){0.f, 0.f, 0.f, 0.f};
            tf[ntl][mt] = (f32x4){0.f, 0.f, 0.f, 0.f};
          }
#pragma unroll
        for (int kb = 0; kb < 2; ++kb) {
          int koff = kb * 32 + (ln >> 4) * 8;
          short8 ya[4], xa[4], wb[4];
#pragma unroll
          for (int mt = 0; mt < 4; mt++) {
            int m = mt * 16 + (ln & 15);
            ya[mt] = *(const short8*)(ystage + m * 80 + koff);
            xa[mt] = cvt8(x + ((t + 1) * 64 + m) * 64 + koff);
          }
#pragma unroll
          for (int ntl = 0; ntl < 4; ntl++)
            wb[ntl] = *(const short8*)(WfxB + ((wv * 4 + ntl) * 16 + (ln & 15)) * 64 + koff);
#pragma unroll
          for (int ntl = 0; ntl < 4; ntl++)
#pragma unroll
            for (int mt = 0; mt < 4; mt++) {
              au[ntl][mt] = __builtin_amdgcn_mfma_f32_16x16x32_bf16(ya[mt], wb[ntl], au[ntl][mt], 0, 0, 0);
              tf[ntl][mt] = __builtin_amdgcn_mfma_f32_16x16x32_bf16(xa[mt], wb[ntl], tf[ntl][mt], 0, 0, 0);
            }
        }
        float mix = msel[t + 1];
        int q = ln >> 4, c15 = ln & 15;
        for (int ntl = 0; ntl < 4; ntl++)
          for (int mt = 0; mt < 4; mt++) {
            float bfx0 = b_fx[(wv * 4 + ntl) * 16 + c15];
#pragma unroll
            for (int r2 = 0; r2 < 4; r2++) {
              float f = mix * fast_tanh(au[ntl][mt][r2] + bfx0) +
                        (1.f - mix) * fast_tanh(tf[ntl][mt][r2] + bfx0);
              int row = mt * 16 + q * 4 + r2;
              fstage[row * 264 + (wv * 4 + ntl) * 16 + c15] = f2bf(f);
            }
          }
        __syncthreads();
#pragma unroll
        for (int it = 0; it < 8; ++it) {       // fstage -> An feat section (A-frag)
          int chunk = it * 256 + tid;
          int kb = chunk >> 8, l = chunk & 63;
          int m = ((chunk >> 6) & 3) * 16 + (l & 15);
          int k = kb * 32 + (l >> 4) * 8;
          *(short8*)(An + chunk * 8) = *(const short8*)(fstage + m * 264 + k);
        }
      }
      __syncthreads();
      if (tid == 0) setflag(fcv, (u32)(t + 1));
      rn = (rn == 2) ? 0 : rn + 1;
    }
  }
}

extern "C" void kernel_launch(void* const* d_in, const int* in_sizes, int n_in,
                              void* d_out, int out_size, void* d_ws, size_t ws_size,
                              hipStream_t stream) {
  const float* x     = (const float*)d_in[0];
  const float* msel  = (const float*)d_in[1];
  const float* W_fx  = (const float*)d_in[2];
  const float* b_fx  = (const float*)d_in[3];
  const float* W_ih  = (const float*)d_in[4];
  const float* W_hh  = (const float*)d_in[5];
  const float* b_ih  = (const float*)d_in[6];
  const float* b_hh  = (const float*)d_in[7];
  const float* W_hx  = (const float*)d_in[8];
  const float* b_hx  = (const float*)d_in[9];
  const float* W_out = (const float*)d_in[10];
  const float* b_out = (const float*)d_in[11];

  uint8_t* ws = (uint8_t*)d_ws;
  u16* Abase = (u16*)ws;                    // ring of 3 x 98304 B
  u16* dbase = (u16*)(ws + 294912);         // ring of 2 x 32768 B
  u16* WoutB = (u16*)(ws + 360448);         // 32768 B
  u16* WfxB  = (u16*)(ws + 393216);         // 32768 B
  u32* flags = (u32*)(ws + 425984);         // 4672 B

  prep_kernel<<<67, 256, 0, stream>>>(x, W_fx, b_fx, W_out, Abase, WoutB, WfxB, flags);
  rnn_kernel<<<NWG, 256, 0, stream>>>(x, msel, W_fx, b_fx, W_ih, W_hh, b_ih, b_hh,
                                      W_hx, b_hx, b_out,
                                      (float*)d_out, Abase, dbase, WoutB, WfxB, flags);
}

// Round 4
// 2922.330 us; speedup vs baseline: 2.5191x; 2.0749x over previous
//
#include <hip/hip_runtime.h>
#include <stdint.h>

typedef unsigned short u16;
typedef unsigned int u32;
typedef unsigned long long u64;
typedef __attribute__((ext_vector_type(8))) short short8;   // 8 x bf16
typedef __attribute__((ext_vector_type(4))) float f32x4;
typedef __attribute__((ext_vector_type(4))) int int4v;

#define SEQ 256
#define GATE_WGS 64
#define D_WGS 8
#define NWG 73          // 64 gate + 8 d + 1 y
#define A_ELE 49152     // elements per A ring slot (bf16)
#define D_ELE 16384

__device__ __forceinline__ u16 f2bf(float f) {
  u32 u = __float_as_uint(f);
  u += 0x7FFFu + ((u >> 16) & 1u);
  return (u16)(u >> 16);
}
__device__ __forceinline__ short8 cvt8(const float* __restrict__ p) {
  short8 r;
#pragma unroll
  for (int j = 0; j < 8; ++j) r[j] = (short)f2bf(p[j]);
  return r;
}
__device__ __forceinline__ short8 cvt8v(const float* __restrict__ p) {  // 2x float4
  f32x4 a = *(const f32x4*)p, b = *(const f32x4*)(p + 4);
  short8 r;
#pragma unroll
  for (int j = 0; j < 4; ++j) { r[j] = (short)f2bf(a[j]); r[4 + j] = (short)f2bf(b[j]); }
  return r;
}
__device__ __forceinline__ float fast_tanh(float x) {
  return 1.0f - 2.0f / (1.0f + __expf(2.0f * x));
}
__device__ __forceinline__ float fast_sig(float x) {
  return 1.0f / (1.0f + __expf(-x));
}

union V16 { short8 s; u64 q[2]; };
// device-coherent 16B load/store (bypass L1/L2 -> L3), fence-free data flow
__device__ __forceinline__ short8 ldc16(const u16* p) {
  V16 v;
  v.q[0] = __hip_atomic_load((const u64*)p,     __ATOMIC_RELAXED, __HIP_MEMORY_SCOPE_AGENT);
  v.q[1] = __hip_atomic_load((const u64*)p + 1, __ATOMIC_RELAXED, __HIP_MEMORY_SCOPE_AGENT);
  return v.s;
}
__device__ __forceinline__ void stc16(u16* p, const u64* s) {
  __hip_atomic_store((u64*)p,     s[0], __ATOMIC_RELAXED, __HIP_MEMORY_SCOPE_AGENT);
  __hip_atomic_store((u64*)p + 1, s[1], __ATOMIC_RELAXED, __HIP_MEMORY_SCOPE_AGENT);
}
__device__ __forceinline__ void pollge(u32* p, u32 v) {
  while (__hip_atomic_load(p, __ATOMIC_RELAXED, __HIP_MEMORY_SCOPE_AGENT) < v) {}
}
__device__ __forceinline__ void setflag(u32* p, u32 v) {
  __hip_atomic_store(p, v, __ATOMIC_RELAXED, __HIP_MEMORY_SCOPE_AGENT);
}
// per-wave store drain: prior sc0sc1 stores reach coherence point before flag
#define VMCNT0() asm volatile("s_waitcnt vmcnt(0)" ::: "memory")

// ---------------------------------------------------------------------------
// Prep: feat_0 -> Abuf slot0 feat section; zero slot0 h section; zero flags.
// A-frag chunk layout: chunk = (kb*4 + mt)*64 + lane; lane holds
// A[m = mt*16 + (lane&15)][k = kb*32 + (lane>>4)*8 + j], j=0..7.
// ---------------------------------------------------------------------------
__global__ void prep_kernel(const float* __restrict__ x, const float* __restrict__ W_fx,
                            const float* __restrict__ b_fx,
                            u16* __restrict__ Abuf0, u32* __restrict__ flags) {
  int b = blockIdx.x, tid = threadIdx.x;
  if (b < 64) {
    int gidx = b * 256 + tid;          // 16384 elements of feat_0 [64][256]
    int chunk = gidx >> 3, j = gidx & 7;
    int kb = chunk >> 8, mt = (chunk >> 6) & 3, l = chunk & 63;
    int m = mt * 16 + (l & 15);
    int c = kb * 32 + (l >> 4) * 8 + j;
    float s = b_fx[c];
    const float* xr = x + m * 64;      // t = 0
    const float* wr = W_fx + c * 64;
    for (int k = 0; k < 64; ++k) s += xr[k] * wr[k];
    Abuf0[chunk * 8 + j] = f2bf(fast_tanh(s));
  } else {
    for (int it = 0; it < 16; ++it) {  // zero h-section of slot0: chunks 2048..6143
      int chunk = it * 256 + tid;
      *(int4v*)(Abuf0 + (2048 + chunk) * 8) = (int4v){0, 0, 0, 0};
    }
    for (int k = 0; k < 5; ++k) {
      int i = k * 256 + tid;
      if (i < 1168) flags[i] = 0u;
    }
  }
}

// ---------------------------------------------------------------------------
// Persistent recurrent kernel. 73 WGs x 256 threads. Fence-free coherent flow:
//   hflag[wg] = t+1 after gate wg stored h_{t+1} ; consumers poll >= t for h_t
//   dflag[dw] = t+1 after d dw stored d_t        ; y polls >= t+1
//   fc        = t+1 after y stored feat_{t+1}    ; gates poll >= t for feat_t
// ---------------------------------------------------------------------------
__global__ void __launch_bounds__(256, 1)
rnn_kernel(const float* __restrict__ x, const float* __restrict__ msel,
           const float* __restrict__ W_fx, const float* __restrict__ b_fx,
           const float* __restrict__ W_ih, const float* __restrict__ W_hh,
           const float* __restrict__ b_ih, const float* __restrict__ b_hh,
           const float* __restrict__ W_hx, const float* __restrict__ b_hx,
           const float* __restrict__ W_out, const float* __restrict__ b_out,
           float* __restrict__ out,
           u16* __restrict__ Abase, u16* __restrict__ dbase,
           u32* __restrict__ flags) {
  __shared__ __attribute__((aligned(16))) char smem[109568];
  const int wgid = blockIdx.x;
  const int tid = threadIdx.x;
  const int wv = tid >> 6, ln = tid & 63;
  u32* hflag = flags;          // stride 16 u32 (64B lines)
  u32* dflag = flags + 1024;
  u32* fcv   = flags + 1152;

  if (wgid < GATE_WGS) {
    // ===== gate WG: 8 hidden units -> 32 gate cols; B-frags in REGISTERS =====
    const int wg = wgid;
    float* red = (float*)smem;                 // [4 wv][8 tile][64][4] = 32KB
    u16* hstage = (u16*)(smem + 32768);        // [4 mt][16 m15][8 u] = 1KB
    short8 Breg[6][2];
#pragma unroll
    for (int kk = 0; kk < 6; ++kk) {
      int kb = wv * 6 + kk;
#pragma unroll
      for (int nt = 0; nt < 2; ++nt) {
        int n = ln & 15, q = ln >> 4;
        int gate = nt * 2 + (n >> 3), unit = n & 7;
        int row = gate * 512 + wg * 8 + unit;
        int k = kb * 32 + q * 8;
        const float* src = (k < 256) ? (W_ih + row * 256 + k) : (W_hh + row * 512 + (k - 256));
        Breg[kk][nt] = cvt8(src);
      }
    }
    float bsum_r[2][4];
#pragma unroll
    for (int it = 0; it < 2; ++it) {
      int u = (it * 256 + tid) & 7;
#pragma unroll
      for (int g = 0; g < 4; ++g) {
        int row = g * 512 + wg * 8 + u;
        bsum_r[it][g] = b_ih[row] + b_hh[row];
      }
    }
    float creg[2] = {0.f, 0.f};
    const int kbW = 8 + (wg >> 2), qW = wg & 3;   // this WG's h region
    int r = 0, rn = 1;
    for (int t = 0; t < SEQ; ++t) {
      if (tid < 64) pollge(&hflag[tid * 16], (u32)t);
      else if (tid == 64) pollge(fcv, (u32)t);
      __syncthreads();
      const u16* A = Abase + r * A_ELE;
      u16* An = Abase + rn * A_ELE;
      short8 a[6][4];
#pragma unroll
      for (int kk = 0; kk < 6; ++kk)
#pragma unroll
        for (int mt = 0; mt < 4; ++mt)
          a[kk][mt] = ldc16(A + (((wv * 6 + kk) * 4 + mt) * 64 + ln) * 8);
      f32x4 acc[2][4];
#pragma unroll
      for (int nt = 0; nt < 2; nt++)
#pragma unroll
        for (int mt = 0; mt < 4; mt++) acc[nt][mt] = (f32x4){0.f, 0.f, 0.f, 0.f};
#pragma unroll
      for (int kk = 0; kk < 6; ++kk)
#pragma unroll
        for (int nt = 0; nt < 2; nt++)
#pragma unroll
          for (int mt = 0; mt < 4; mt++)
            acc[nt][mt] = __builtin_amdgcn_mfma_f32_16x16x32_bf16(a[kk][mt], Breg[kk][nt], acc[nt][mt], 0, 0, 0);
      // one-shot 4-wave reduction staging
#pragma unroll
      for (int nt = 0; nt < 2; nt++)
#pragma unroll
        for (int mt = 0; mt < 4; mt++)
          *(f32x4*)(red + ((wv * 8 + nt * 4 + mt) * 64 + ln) * 4) = acc[nt][mt];
      __syncthreads();
      // LSTM cell: 512 (m,u) items, 2/thread; sum 4 wave-partials inline
#pragma unroll
      for (int it = 0; it < 2; ++it) {
        int item = it * 256 + tid;
        int m = item >> 3, u = item & 7;
        int mt = m >> 4, lq = ((m & 15) >> 2) * 16, reg = m & 3;
        float g4[4];
#pragma unroll
        for (int g = 0; g < 4; ++g) {
          float s = bsum_r[it][g];
          int base = ((g >> 1) * 4 + mt) * 64 + lq + (g & 1) * 8 + u;
#pragma unroll
          for (int w = 0; w < 4; ++w) s += red[(w * 8 * 64 + base) * 4 + reg];
          g4[g] = s;
        }
        float ii = fast_sig(g4[0]), ff = fast_sig(g4[1]);
        float gg = fast_tanh(g4[2]), oo = fast_sig(g4[3]);
        float cn = ff * creg[it] + ii * gg;
        creg[it] = cn;
        float h = oo * fast_tanh(cn);
        hstage[(mt * 16 + (m & 15)) * 8 + u] = f2bf(h);
      }
      __syncthreads();
      if (tid < 64) {   // 16B coherent stores of this WG's 1KB h region
        int mt2 = tid >> 4, m15 = tid & 15;
        u16* dst = An + (((kbW * 4 + mt2) * 64 + qW * 16 + m15) * 8);
        stc16(dst, (const u64*)(hstage + tid * 8));
        VMCNT0();
      }
      __syncthreads();
      if (tid == 0) setflag(&hflag[wg * 16], (u32)(t + 1));
      r = rn; rn = (rn == 2) ? 0 : rn + 1;
    }
  } else if (wgid < GATE_WGS + D_WGS) {
    // ===== d WG: d = tanh(h @ Whx^T + b_hx), 32 DEC cols; B in registers =====
    const int dw = wgid - GATE_WGS;
    float* red = (float*)smem;                 // 32KB
    u16* dstage = (u16*)(smem + 32768);        // [4 mt][4 q][16 m15][8 j] = 4KB
    short8 Breg[4][2];
#pragma unroll
    for (int kk = 0; kk < 4; ++kk) {
      int kbh = wv * 4 + kk;
#pragma unroll
      for (int nt = 0; nt < 2; ++nt) {
        int n = ln & 15, q = ln >> 4;
        int row = dw * 32 + nt * 16 + n;
        int k = kbh * 32 + q * 8;
        Breg[kk][nt] = cvt8(W_hx + row * 512 + k);
      }
    }
    float bias_r[8];
#pragma unroll
    for (int it = 0; it < 8; ++it) bias_r[it] = b_hx[dw * 32 + ((it * 256 + tid) & 31)];
    int r = 0, rn = 1;
    for (int t = 0; t < SEQ; ++t) {
      if (tid < 64) pollge(&hflag[tid * 16], (u32)t);
      __syncthreads();
      const u16* A = Abase + r * A_ELE;
      u16* dbufR = dbase + (t & 1) * D_ELE;
      short8 a[4][4];
#pragma unroll
      for (int kk = 0; kk < 4; ++kk)
#pragma unroll
        for (int mt = 0; mt < 4; ++mt)
          a[kk][mt] = ldc16(A + (((8 + wv * 4 + kk) * 4 + mt) * 64 + ln) * 8);
      f32x4 acc[2][4];
#pragma unroll
      for (int nt = 0; nt < 2; nt++)
#pragma unroll
        for (int mt = 0; mt < 4; mt++) acc[nt][mt] = (f32x4){0.f, 0.f, 0.f, 0.f};
#pragma unroll
      for (int kk = 0; kk < 4; ++kk)
#pragma unroll
        for (int nt = 0; nt < 2; nt++)
#pragma unroll
          for (int mt = 0; mt < 4; mt++)
            acc[nt][mt] = __builtin_amdgcn_mfma_f32_16x16x32_bf16(a[kk][mt], Breg[kk][nt], acc[nt][mt], 0, 0, 0);
#pragma unroll
      for (int nt = 0; nt < 2; nt++)
#pragma unroll
        for (int mt = 0; mt < 4; mt++)
          *(f32x4*)(red + ((wv * 8 + nt * 4 + mt) * 64 + ln) * 4) = acc[nt][mt];
      __syncthreads();
#pragma unroll
      for (int it = 0; it < 8; ++it) {          // 2048 outputs, 8/thread
        int item = it * 256 + tid;
        int m = item >> 5, c = item & 31;
        int mt = m >> 4, lq = ((m & 15) >> 2) * 16, reg = m & 3;
        float s = bias_r[it];
        int base = ((c >> 4) * 4 + mt) * 64 + lq + (c & 15);
#pragma unroll
        for (int w = 0; w < 4; ++w) s += red[(w * 8 * 64 + base) * 4 + reg];
        dstage[((mt * 4 + (c >> 3)) * 16 + (m & 15)) * 8 + (c & 7)] = f2bf(fast_tanh(s));
      }
      __syncthreads();
      {   // 256 x 16B coherent stores: d region = 4KB contiguous
        stc16(dbufR + (dw * 256 + tid) * 8, (const u64*)(dstage + tid * 8));
        VMCNT0();
      }
      __syncthreads();
      if (tid == 0) setflag(&dflag[dw * 16], (u32)(t + 1));
      r = rn; rn = (rn == 2) ? 0 : rn + 1;
    }
  } else {
    // ===== y WG: y = d@Wout^T + b_out; feat_{t+1} = mix*fe(y)+(1-mix)*fe(x) =====
    float* red = (float*)smem;                 // [4 wv][16 tile][64][4] = 64KB
    u16* ystage = (u16*)(smem + 65536);        // [64][80] = 10240B
    u16* fstage = (u16*)(smem + 75776);        // [64][264] = 33792B
    const int c15 = ln & 15, qq = ln >> 4;
    short8 WoR[2][4], WfR[2][4];
#pragma unroll
    for (int kk = 0; kk < 2; ++kk) {
      int koffo = (wv * 2 + kk) * 32 + qq * 8;   // W_out K-offset (K=256)
      int kofff = kk * 32 + qq * 8;              // W_fx K-offset (K=64)
#pragma unroll
      for (int nt = 0; nt < 4; ++nt) {
        WoR[kk][nt] = cvt8(W_out + (nt * 16 + c15) * 256 + koffo);
        WfR[kk][nt] = cvt8(W_fx + ((wv * 4 + nt) * 16 + c15) * 64 + kofff);
      }
    }
    float bout_r = b_out[wv * 16 + c15];
    float bfx_r[4];
#pragma unroll
    for (int nt = 0; nt < 4; ++nt) bfx_r[nt] = b_fx[(wv * 4 + nt) * 16 + c15];

    int rn = 1;
    for (int t = 0; t < SEQ; ++t) {
      // prefetch x[t+1] + msel[t+1] before the poll (plain cached loads)
      short8 xa[2][4];
      float mix = 0.f;
      if (t < SEQ - 1) {
        mix = msel[t + 1];
#pragma unroll
        for (int kb = 0; kb < 2; ++kb)
#pragma unroll
          for (int mt = 0; mt < 4; ++mt)
            xa[kb][mt] = cvt8v(x + ((t + 1) * 64 + mt * 16 + c15) * 64 + kb * 32 + qq * 8);
      }
      if (tid < 8) pollge(&dflag[tid * 16], (u32)(t + 1));
      __syncthreads();
      const u16* dbufR = dbase + (t & 1) * D_ELE;
      u16* An = Abase + rn * A_ELE;
      short8 da[2][4];
#pragma unroll
      for (int kk = 0; kk < 2; ++kk)
#pragma unroll
        for (int mt = 0; mt < 4; ++mt)
          da[kk][mt] = ldc16(dbufR + (((wv * 2 + kk) * 4 + mt) * 64 + ln) * 8);
      f32x4 acc[4][4];
#pragma unroll
      for (int nt = 0; nt < 4; nt++)
#pragma unroll
        for (int mt = 0; mt < 4; mt++) acc[nt][mt] = (f32x4){0.f, 0.f, 0.f, 0.f};
#pragma unroll
      for (int kk = 0; kk < 2; ++kk)
#pragma unroll
        for (int nt = 0; nt < 4; nt++)
#pragma unroll
          for (int mt = 0; mt < 4; mt++)
            acc[nt][mt] = __builtin_amdgcn_mfma_f32_16x16x32_bf16(da[kk][mt], WoR[kk][nt], acc[nt][mt], 0, 0, 0);
#pragma unroll
      for (int nt = 0; nt < 4; nt++)
#pragma unroll
        for (int mt = 0; mt < 4; mt++)
          *(f32x4*)(red + ((wv * 16 + nt * 4 + mt) * 64 + ln) * 4) = acc[nt][mt];
      __syncthreads();
      // wave wv finalizes output cols [wv*16, wv*16+16)
#pragma unroll
      for (int mt = 0; mt < 4; ++mt) {
        f32x4 s = (f32x4){0.f, 0.f, 0.f, 0.f};
#pragma unroll
        for (int w2 = 0; w2 < 4; ++w2)
          s += *(const f32x4*)(red + ((w2 * 16 + wv * 4 + mt) * 64 + ln) * 4);
#pragma unroll
        for (int r2 = 0; r2 < 4; ++r2) {
          float yv = s[r2] + bout_r;
          int row = mt * 16 + qq * 4 + r2;
          out[t * 4096 + row * 64 + wv * 16 + c15] = yv;   // f32 output (plain)
          ystage[row * 80 + wv * 16 + c15] = f2bf(yv);
        }
      }
      __syncthreads();
      if (t < SEQ - 1) {
        f32x4 au[4][4], tf[4][4];
#pragma unroll
        for (int nt = 0; nt < 4; nt++)
#pragma unroll
          for (int mt = 0; mt < 4; mt++) {
            au[nt][mt] = (f32x4){0.f, 0.f, 0.f, 0.f};
            tf[nt][mt] = (f32x4){0.f, 0.f, 0.f, 0.f};
          }
#pragma unroll
        for (int kb = 0; kb < 2; ++kb) {
          int koff = kb * 32 + qq * 8;
          short8 ya[4];
#pragma unroll
          for (int mt = 0; mt < 4; mt++)
            ya[mt] = *(const short8*)(ystage + (mt * 16 + c15) * 80 + koff);
#pragma unroll
          for (int nt = 0; nt < 4; nt++)
#pragma unroll
            for (int mt = 0; mt < 4; mt++) {
              au[nt][mt] = __builtin_amdgcn_mfma_f32_16x16x32_bf16(ya[mt], WfR[kb][nt], au[nt][mt], 0, 0, 0);
              tf[nt][mt] = __builtin_amdgcn_mfma_f32_16x16x32_bf16(xa[kb][mt], WfR[kb][nt], tf[nt][mt], 0, 0, 0);
            }
        }
#pragma unroll
        for (int nt = 0; nt < 4; nt++)
#pragma unroll
          for (int mt = 0; mt < 4; mt++)
#pragma unroll
            for (int r2 = 0; r2 < 4; r2++) {
              float f = mix * fast_tanh(au[nt][mt][r2] + bfx_r[nt]) +
                        (1.f - mix) * fast_tanh(tf[nt][mt][r2] + bfx_r[nt]);
              int row = mt * 16 + qq * 4 + r2;
              fstage[row * 264 + (wv * 4 + nt) * 16 + c15] = f2bf(f);
            }
        __syncthreads();
#pragma unroll
        for (int it = 0; it < 8; ++it) {       // fstage -> An feat section, coherent
          int chunk = it * 256 + tid;
          int kb = chunk >> 8, l = chunk & 63;
          int m = ((chunk >> 6) & 3) * 16 + (l & 15);
          int k = kb * 32 + (l >> 4) * 8;
          V16 v; v.s = *(const short8*)(fstage + m * 264 + k);
          stc16(An + chunk * 8, v.q);
        }
        VMCNT0();
        __syncthreads();
        if (tid == 0) setflag(fcv, (u32)(t + 1));
      }
      rn = (rn == 2) ? 0 : rn + 1;
    }
  }
}

extern "C" void kernel_launch(void* const* d_in, const int* in_sizes, int n_in,
                              void* d_out, int out_size, void* d_ws, size_t ws_size,
                              hipStream_t stream) {
  const float* x     = (const float*)d_in[0];
  const float* msel  = (const float*)d_in[1];
  const float* W_fx  = (const float*)d_in[2];
  const float* b_fx  = (const float*)d_in[3];
  const float* W_ih  = (const float*)d_in[4];
  const float* W_hh  = (const float*)d_in[5];
  const float* b_ih  = (const float*)d_in[6];
  const float* b_hh  = (const float*)d_in[7];
  const float* W_hx  = (const float*)d_in[8];
  const float* b_hx  = (const float*)d_in[9];
  const float* W_out = (const float*)d_in[10];
  const float* b_out = (const float*)d_in[11];

  uint8_t* ws = (uint8_t*)d_ws;
  u16* Abase = (u16*)ws;                    // ring of 3 x 98304 B
  u16* dbase = (u16*)(ws + 294912);         // ring of 2 x 32768 B
  u32* flags = (u32*)(ws + 360448);         // 4672 B

  prep_kernel<<<65, 256, 0, stream>>>(x, W_fx, b_fx, Abase, flags);
  rnn_kernel<<<NWG, 256, 0, stream>>>(x, msel, W_fx, b_fx, W_ih, W_hh, b_ih, b_hh,
                                      W_hx, b_hx, W_out, b_out,
                                      (float*)d_out, Abase, dbase, flags);
}